// Round 1
// baseline (793.878 us; speedup 1.0000x reference)
//
#include <hip/hip_runtime.h>
#include <cstdint>

#define B_ 8
#define N_ 2048
#define D_ 1024

typedef __attribute__((ext_vector_type(8))) short bf16x8;
typedef __attribute__((ext_vector_type(4))) float f32x4;

__device__ __forceinline__ ushort f2bf(float f) {
  union { float f; uint32_t u; } v; v.f = f;
  return (ushort)((v.u + 0x7fffu + ((v.u >> 16) & 1u)) >> 16);
}

__device__ __forceinline__ void gload_lds16(const void* g, void* l) {
  __builtin_amdgcn_global_load_lds(
      (const __attribute__((address_space(1))) void*)(uintptr_t)g,
      (__attribute__((address_space(3))) void*)(uint32_t)(uintptr_t)l,
      16, 0, 0);
}

// Stage a 128-row x 64-col bf16 tile (row-major, row stride ldg elems) into LDS
// (row-major 128x64, no padding -- required by global_load_lds lane mapping).
__device__ __forceinline__ void stage_tile(const ushort* g, int ldg, ushort* lds, int tid) {
  int wave = tid >> 6, lane = tid & 63;
  const ushort* gp = g + (size_t)(wave * 8 + (lane >> 3)) * ldg + ((lane & 7) * 8);
  ushort* lp = lds + wave * 512;  // wave-uniform base; HW adds lane*16B
#pragma unroll
  for (int q = 0; q < 4; ++q) {
    gload_lds16(gp, lp);
    gp += (size_t)32 * ldg;
    lp += 2048;
  }
}

struct GParams {
  const ushort* A; const ushort* B;
  long sAz, sBz;
  int lda, ldb, K;
  // epilogue params (used per-mode)
  ushort* u_out;          // mode 0
  const float* gates;     // mode 1, 2
  ushort* vT_out;         // mode 1
  const float* r_in;      // mode 2
  float* r_out;           // mode 2
  ushort* c_out;          // mode 2
  float* S;               // mode 2 (atomic out), mode 3 (in)
  const float* condp;     // mode 2
  float* field;           // mode 3
};

// NT GEMM: C[m][n] = sum_k A[m][k]*B[n][k].  128x128 tile, BK=64, 256 thr.
// MODE 0: u epilogue   MODE 1: gated+transposed values   MODE 2: r/c epilogue
// MODE 3: field scaled by 1/S
template<int MODE>
__global__ __launch_bounds__(256, 2)
void gemm_nt(GParams p) {
  __shared__ __align__(16) ushort sA[128 * 64];
  __shared__ __align__(16) ushort sB[128 * 64];
  int tid = threadIdx.x;
  int z = blockIdx.z;
  const ushort* Ab = p.A + (size_t)z * p.sAz + (size_t)blockIdx.y * 128 * p.lda;
  const ushort* Bb = p.B + (size_t)z * p.sBz + (size_t)blockIdx.x * 128 * p.ldb;

  f32x4 acc[4][4];
#pragma unroll
  for (int i = 0; i < 4; ++i)
#pragma unroll
    for (int j = 0; j < 4; ++j) acc[i][j] = (f32x4)0.f;

  int lane = tid & 63, wid = tid >> 6;
  int wm = wid >> 1, wn = wid & 1, quad = lane >> 4, tn = lane & 15;

  for (int k0 = 0; k0 < p.K; k0 += 64) {
    stage_tile(Ab + k0, p.lda, sA, tid);
    stage_tile(Bb + k0, p.ldb, sB, tid);
    __syncthreads();
#pragma unroll
    for (int kk = 0; kk < 64; kk += 32) {
      bf16x8 av[4], bv[4];
#pragma unroll
      for (int t = 0; t < 4; ++t) {
        av[t] = *(const bf16x8*)(sA + (wm * 64 + t * 16 + tn) * 64 + kk + quad * 8);
        bv[t] = *(const bf16x8*)(sB + (wn * 64 + t * 16 + tn) * 64 + kk + quad * 8);
      }
#pragma unroll
      for (int i = 0; i < 4; ++i)
#pragma unroll
        for (int j = 0; j < 4; ++j)
          acc[i][j] = __builtin_amdgcn_mfma_f32_16x16x32_bf16(av[i], bv[j], acc[i][j], 0, 0, 0);
    }
    __syncthreads();
  }

  // C/D layout: col = lane&15, row = quad*4 + reg  (verified m89/m91)
  int row0 = blockIdx.y * 128 + wm * 64 + quad * 4;
  int col0 = blockIdx.x * 128 + wn * 64 + tn;

  if constexpr (MODE == 0) {
    // acc = a = X@W_in^T.  Pair-normalize (x,y)=(a[2p],a[2p+1]) -> ca,sa.
    bool even = (tn & 1) == 0;
#pragma unroll
    for (int i = 0; i < 4; ++i) {
      int rbase = row0 + i * 16;
#pragma unroll
      for (int j = 0; j < 4; ++j) {
        int col = col0 + j * 16;
        int pp = col >> 1;
        int d = even ? pp : 512 + pp;
#pragma unroll
        for (int r = 0; r < 4; ++r) {
          float v = acc[i][j][r];
          float w = __shfl_xor(v, 1);   // partner holds the adjacent column
          float xe = (even ? v : w) + 1e-8f;
          float ye = (even ? w : v) + 1e-8f;
          float rinv = rsqrtf(xe * xe + ye * ye);
          float val = (even ? xe : ye) * rinv;
          p.u_out[(size_t)(rbase + r) * 1024 + d] = f2bf(val);
        }
      }
    }
  } else if constexpr (MODE == 1) {
    // acc = X@W_out^T.  values = gate_row * acc; store transposed vT[b][d][n].
#pragma unroll
    for (int i = 0; i < 4; ++i) {
      int rbase = row0 + i * 16;            // flat b*N+n, rbase%4==0
      float g0 = p.gates[rbase + 0];
      float g1 = p.gates[rbase + 1];
      float g2 = p.gates[rbase + 2];
      float g3 = p.gates[rbase + 3];
      int b = rbase >> 11;
      int nloc = rbase & 2047;
#pragma unroll
      for (int j = 0; j < 4; ++j) {
        int d = col0 + j * 16;
        ushort4 pk;
        pk.x = f2bf(acc[i][j][0] * g0);
        pk.y = f2bf(acc[i][j][1] * g1);
        pk.z = f2bf(acc[i][j][2] * g2);
        pk.w = f2bf(acc[i][j][3] * g3);
        *(ushort4*)(p.vT_out + ((size_t)b * 1024 + d) * 2048 + nloc) = pk;
      }
    }
  } else if constexpr (MODE == 2) {
    // acc = u@u^T.  r_new + coupling + rowsums.
    float cond = p.condp[0];
    cond = fminf(5.f, fmaxf(-5.f, cond));
    const float* g = p.gates + (size_t)z * 2048;
    float rs[4][4];
#pragma unroll
    for (int i = 0; i < 4; ++i)
#pragma unroll
      for (int r = 0; r < 4; ++r) rs[i][r] = 0.f;
#pragma unroll
    for (int i = 0; i < 4; ++i) {
      int nb = row0 + i * 16;
#pragma unroll
      for (int j = 0; j < 4; ++j) {
        int m = col0 + j * 16;
        float gm = g[m];
#pragma unroll
        for (int r = 0; r < 4; ++r) {
          int n = nb + r;
          size_t idx = ((size_t)z * 2048 + n) * 2048 + m;
          float rinst = acc[i][j][r] * (1.0f / 512.0f);
          float rnew = 0.7f * p.r_in[idx] + 0.3f * rinst;
          rnew = fminf(2.f, fmaxf(-2.f, rnew));
          p.r_out[idx] = rnew;
          float cv = 0.f;
          if (m != n) cv = gm * g[n] / (1.f + __expf(-cond * rnew));
          p.c_out[idx] = f2bf(cv);
          rs[i][r] += cv;
        }
      }
    }
    // reduce over the 16 lanes of each quad (they share rows), one atomic each
#pragma unroll
    for (int i = 0; i < 4; ++i)
#pragma unroll
      for (int r = 0; r < 4; ++r) {
        float s = rs[i][r];
        s += __shfl_xor(s, 1);
        s += __shfl_xor(s, 2);
        s += __shfl_xor(s, 4);
        s += __shfl_xor(s, 8);
        if (tn == 0) atomicAdd(p.S + (size_t)z * 2048 + row0 + i * 16 + r, s);
      }
  } else {
    // MODE 3: acc = c@v.  Scale rows by 1/(S+1e-8).
#pragma unroll
    for (int i = 0; i < 4; ++i) {
      int nb = row0 + i * 16;
      float sc[4];
#pragma unroll
      for (int r = 0; r < 4; ++r) sc[r] = 1.f / (p.S[(size_t)z * 2048 + nb + r] + 1e-8f);
#pragma unroll
      for (int j = 0; j < 4; ++j) {
        int d = col0 + j * 16;
#pragma unroll
        for (int r = 0; r < 4; ++r)
          p.field[((size_t)z * 2048 + nb + r) * 1024 + d] = acc[i][j][r] * sc[r];
      }
    }
  }
}

__global__ void cvt_bf16(const float* __restrict__ src, ushort* __restrict__ dst, int n4) {
  int i = blockIdx.x * blockDim.x + threadIdx.x;
  if (i < n4) {
    float4 f = ((const float4*)src)[i];
    ushort4 o;
    o.x = f2bf(f.x); o.y = f2bf(f.y); o.z = f2bf(f.z); o.w = f2bf(f.w);
    ((ushort4*)dst)[i] = o;
  }
}

extern "C" void kernel_launch(void* const* d_in, const int* in_sizes, int n_in,
                              void* d_out, int out_size, void* d_ws, size_t ws_size,
                              hipStream_t stream) {
  const float* states = (const float*)d_in[0];
  const float* gates  = (const float*)d_in[1];
  const float* r_acc  = (const float*)d_in[2];
  const float* W_in   = (const float*)d_in[3];
  const float* W_out  = (const float*)d_in[4];
  const float* condp  = (const float*)d_in[5];

  float* field = (float*)d_out;                       // (B,N,D)
  float* r_out = field + (size_t)B_ * N_ * D_;        // (B,N,N)

  char* w = (char*)d_ws;
  ushort* Xb  = (ushort*)w; w += (size_t)B_ * N_ * D_ * 2;   // 33.5 MB
  ushort* Wib = (ushort*)w; w += (size_t)D_ * D_ * 2;        // 2 MB
  ushort* Wob = (ushort*)w; w += (size_t)D_ * D_ * 2;        // 2 MB
  ushort* U   = (ushort*)w; w += (size_t)B_ * N_ * D_ * 2;   // 33.5 MB
  ushort* VT  = (ushort*)w; w += (size_t)B_ * D_ * N_ * 2;   // 33.5 MB
  ushort* C   = (ushort*)w; w += (size_t)B_ * N_ * N_ * 2;   // 67 MB
  float*  S   = (float*)w;                                   // 64 KB

  hipMemsetAsync(S, 0, (size_t)B_ * N_ * 4, stream);

  cvt_bf16<<<dim3(B_ * N_ * D_ / 4 / 256), 256, 0, stream>>>(states, Xb, B_ * N_ * D_ / 4);
  cvt_bf16<<<dim3(D_ * D_ / 4 / 256), 256, 0, stream>>>(W_in, Wib, D_ * D_ / 4);
  cvt_bf16<<<dim3(D_ * D_ / 4 / 256), 256, 0, stream>>>(W_out, Wob, D_ * D_ / 4);

  // GEMM 1a: a = X@W_in^T  -> u
  GParams p0{};
  p0.A = Xb; p0.B = Wib; p0.sAz = 0; p0.sBz = 0;
  p0.lda = D_; p0.ldb = D_; p0.K = D_;
  p0.u_out = U;
  gemm_nt<0><<<dim3(8, 128, 1), 256, 0, stream>>>(p0);

  // GEMM 1b: values = g*(X@W_out^T) -> vT
  GParams p1{};
  p1.A = Xb; p1.B = Wob; p1.sAz = 0; p1.sBz = 0;
  p1.lda = D_; p1.ldb = D_; p1.K = D_;
  p1.gates = gates; p1.vT_out = VT;
  gemm_nt<1><<<dim3(8, 128, 1), 256, 0, stream>>>(p1);

  // GEMM 2: r_inst = u@u^T -> r_new (out), c (ws), S (ws)
  GParams p2{};
  p2.A = U; p2.B = U; p2.sAz = (long)N_ * D_; p2.sBz = (long)N_ * D_;
  p2.lda = D_; p2.ldb = D_; p2.K = D_;
  p2.gates = gates; p2.r_in = r_acc; p2.r_out = r_out;
  p2.c_out = C; p2.S = S; p2.condp = condp;
  gemm_nt<2><<<dim3(16, 16, 8), 256, 0, stream>>>(p2);

  // GEMM 3: field = (c@v) / S
  GParams p3{};
  p3.A = C; p3.B = VT; p3.sAz = (long)N_ * N_; p3.sBz = (long)D_ * N_;
  p3.lda = N_; p3.ldb = N_; p3.K = N_;
  p3.S = S; p3.field = field;
  gemm_nt<3><<<dim3(8, 16, 8), 256, 0, stream>>>(p3);
}

// Round 2
// 653.553 us; speedup vs baseline: 1.2147x; 1.2147x over previous
//
#include <hip/hip_runtime.h>
#include <cstdint>

#define B_ 8
#define N_ 2048
#define D_ 1024

typedef __attribute__((ext_vector_type(8))) short bf16x8;
typedef __attribute__((ext_vector_type(4))) float f32x4;

__device__ __forceinline__ ushort f2bf(float f) {
  union { float f; uint32_t u; } v; v.f = f;
  return (ushort)((v.u + 0x7fffu + ((v.u >> 16) & 1u)) >> 16);
}

__device__ __forceinline__ void gload_lds16(const void* g, void* l) {
  __builtin_amdgcn_global_load_lds(
      (const __attribute__((address_space(1))) void*)(uintptr_t)g,
      (__attribute__((address_space(3))) void*)(uint32_t)(uintptr_t)l,
      16, 0, 0);
}

// Stage a 128-row x 64-col bf16 tile (row-major, row stride ldg elems) into LDS
// (row-major 128x64, no padding -- required by global_load_lds lane mapping).
__device__ __forceinline__ void stage_tile(const ushort* g, int ldg, ushort* lds, int tid) {
  int wave = tid >> 6, lane = tid & 63;
  const ushort* gp = g + (size_t)(wave * 8 + (lane >> 3)) * ldg + ((lane & 7) * 8);
  ushort* lp = lds + wave * 512;  // wave-uniform base; HW adds lane*16B
#pragma unroll
  for (int q = 0; q < 4; ++q) {
    gload_lds16(gp, lp);
    gp += (size_t)32 * ldg;
    lp += 2048;
  }
}

// 4x4 in-register transpose across the 4-lane subgroup (lane&3).
// In:  lane s holds column s of a 4x4 tile in v[0..3] (v[r] = row r).
// Out: lane s holds row s; v[c] = column c.
__device__ __forceinline__ void quad_transpose(float v[4], int s) {
  float x0 = __shfl_xor((s & 1) ? v[0] : v[1], 1);
  if (s & 1) v[0] = x0; else v[1] = x0;
  float x1 = __shfl_xor((s & 1) ? v[2] : v[3], 1);
  if (s & 1) v[2] = x1; else v[3] = x1;
  float y0 = __shfl_xor((s & 2) ? v[0] : v[2], 2);
  if (s & 2) v[0] = y0; else v[2] = y0;
  float y1 = __shfl_xor((s & 2) ? v[1] : v[3], 2);
  if (s & 2) v[1] = y1; else v[3] = y1;
}

struct GParams {
  const ushort* A; const ushort* B;
  long sAz, sBz;
  int lda, ldb, K;
  // epilogue params (used per-mode)
  ushort* u_out;          // mode 0
  const float* gates;     // mode 1, 2
  ushort* vT_out;         // mode 1
  const float* r_in;      // mode 2
  float* r_out;           // mode 2
  ushort* c_out;          // mode 2
  float* S;               // mode 2 (atomic out), mode 3 (in)
  const float* condp;     // mode 2
  float* field;           // mode 3
};

// NT GEMM: C[m][n] = sum_k A[m][k]*B[n][k].  128x128 tile, BK=64, 256 thr.
// MODE 0: u epilogue   MODE 1: gated+transposed values   MODE 2: r/c epilogue
// MODE 3: field scaled by 1/S
template<int MODE>
__global__ __launch_bounds__(256, 4)
void gemm_nt(GParams p) {
  __shared__ __align__(16) ushort sA[128 * 64];
  __shared__ __align__(16) ushort sB[128 * 64];
  int tid = threadIdx.x;
  int z = blockIdx.z;
  const ushort* Ab = p.A + (size_t)z * p.sAz + (size_t)blockIdx.y * 128 * p.lda;
  const ushort* Bb = p.B + (size_t)z * p.sBz + (size_t)blockIdx.x * 128 * p.ldb;

  f32x4 acc[4][4];
#pragma unroll
  for (int i = 0; i < 4; ++i)
#pragma unroll
    for (int j = 0; j < 4; ++j) acc[i][j] = (f32x4)0.f;

  int lane = tid & 63, wid = tid >> 6;
  int wm = wid >> 1, wn = wid & 1, quad = lane >> 4, tn = lane & 15;

  for (int k0 = 0; k0 < p.K; k0 += 64) {
    stage_tile(Ab + k0, p.lda, sA, tid);
    stage_tile(Bb + k0, p.ldb, sB, tid);
    __syncthreads();
#pragma unroll
    for (int kk = 0; kk < 64; kk += 32) {
      bf16x8 av[4], bv[4];
#pragma unroll
      for (int t = 0; t < 4; ++t) {
        av[t] = *(const bf16x8*)(sA + (wm * 64 + t * 16 + tn) * 64 + kk + quad * 8);
        bv[t] = *(const bf16x8*)(sB + (wn * 64 + t * 16 + tn) * 64 + kk + quad * 8);
      }
#pragma unroll
      for (int i = 0; i < 4; ++i)
#pragma unroll
        for (int j = 0; j < 4; ++j)
          acc[i][j] = __builtin_amdgcn_mfma_f32_16x16x32_bf16(av[i], bv[j], acc[i][j], 0, 0, 0);
    }
    __syncthreads();
  }

  // C/D layout: col = lane&15, row = quad*4 + reg  (verified m89/m91)
  int row0 = blockIdx.y * 128 + wm * 64 + quad * 4;   // +i*16 (+reg / +s after transpose)
  int colbase = blockIdx.x * 128 + wn * 64;            // +j*16 +tn (pre-transpose)
  int s = tn & 3, t4 = tn & 12;

  if constexpr (MODE == 0) {
    // acc = a = X@W_in^T.  Pair-normalize (x,y)=(a[2p],a[2p+1]) -> ca,sa.
    // After transpose each lane owns row n, 4 consecutive cols = 2 pairs.
#pragma unroll
    for (int i = 0; i < 4; ++i) {
      int n = row0 + i * 16 + s;
#pragma unroll
      for (int j = 0; j < 4; ++j) {
        float v[4] = {acc[i][j][0], acc[i][j][1], acc[i][j][2], acc[i][j][3]};
        quad_transpose(v, s);
        int c0 = colbase + j * 16 + t4;        // multiple of 4
        float xe0 = v[0] + 1e-8f, ye0 = v[1] + 1e-8f;
        float xe1 = v[2] + 1e-8f, ye1 = v[3] + 1e-8f;
        float ri0 = rsqrtf(xe0 * xe0 + ye0 * ye0);
        float ri1 = rsqrtf(xe1 * xe1 + ye1 * ye1);
        int pp = c0 >> 1;                       // even
        ushort2 ca; ca.x = f2bf(xe0 * ri0); ca.y = f2bf(xe1 * ri1);
        ushort2 sa; sa.x = f2bf(ye0 * ri0); sa.y = f2bf(ye1 * ri1);
        *(ushort2*)(p.u_out + (size_t)n * 1024 + pp) = ca;
        *(ushort2*)(p.u_out + (size_t)n * 1024 + 512 + pp) = sa;
      }
    }
  } else if constexpr (MODE == 1) {
    // acc = X@W_out^T.  values = gate_row * acc; store transposed vT[b][d][n].
    // No transpose: regs already run along n (consecutive rows), which is the
    // contiguous dim of vT.
#pragma unroll
    for (int i = 0; i < 4; ++i) {
      int rbase = row0 + i * 16;            // flat b*N+n, rbase%4==0
      float g0 = p.gates[rbase + 0];
      float g1 = p.gates[rbase + 1];
      float g2 = p.gates[rbase + 2];
      float g3 = p.gates[rbase + 3];
      int b = rbase >> 11;
      int nloc = rbase & 2047;
#pragma unroll
      for (int j = 0; j < 4; ++j) {
        int d = colbase + j * 16 + tn;
        ushort4 pk;
        pk.x = f2bf(acc[i][j][0] * g0);
        pk.y = f2bf(acc[i][j][1] * g1);
        pk.z = f2bf(acc[i][j][2] * g2);
        pk.w = f2bf(acc[i][j][3] * g3);
        *(ushort4*)(p.vT_out + ((size_t)b * 1024 + d) * 2048 + nloc) = pk;
      }
    }
  } else if constexpr (MODE == 2) {
    // acc = u@u^T.  r_new + coupling + rowsums, all vectorized x4 via transpose.
    float cond = p.condp[0];
    cond = fminf(5.f, fmaxf(-5.f, cond));
    const float* g = p.gates + (size_t)z * 2048;
    float rs[4];
#pragma unroll
    for (int i = 0; i < 4; ++i) rs[i] = 0.f;
#pragma unroll
    for (int i = 0; i < 4; ++i) {
      int n = row0 + i * 16 + s;
      float gn = g[n];
#pragma unroll
      for (int j = 0; j < 4; ++j) {
        float v[4] = {acc[i][j][0], acc[i][j][1], acc[i][j][2], acc[i][j][3]};
        quad_transpose(v, s);
        int m0 = colbase + j * 16 + t4;
        size_t idx = ((size_t)z * 2048 + n) * 2048 + m0;
        float4 rin = *(const float4*)(p.r_in + idx);
        float4 gm = *(const float4*)(g + m0);
        float4 ro;
        ro.x = fminf(2.f, fmaxf(-2.f, 0.7f * rin.x + v[0] * (0.3f / 512.0f)));
        ro.y = fminf(2.f, fmaxf(-2.f, 0.7f * rin.y + v[1] * (0.3f / 512.0f)));
        ro.z = fminf(2.f, fmaxf(-2.f, 0.7f * rin.z + v[2] * (0.3f / 512.0f)));
        ro.w = fminf(2.f, fmaxf(-2.f, 0.7f * rin.w + v[3] * (0.3f / 512.0f)));
        *(float4*)(p.r_out + idx) = ro;
        float cv0 = (m0 + 0 != n) ? gn * gm.x / (1.f + __expf(-cond * ro.x)) : 0.f;
        float cv1 = (m0 + 1 != n) ? gn * gm.y / (1.f + __expf(-cond * ro.y)) : 0.f;
        float cv2 = (m0 + 2 != n) ? gn * gm.z / (1.f + __expf(-cond * ro.z)) : 0.f;
        float cv3 = (m0 + 3 != n) ? gn * gm.w / (1.f + __expf(-cond * ro.w)) : 0.f;
        ushort4 cpk;
        cpk.x = f2bf(cv0); cpk.y = f2bf(cv1); cpk.z = f2bf(cv2); cpk.w = f2bf(cv3);
        *(ushort4*)(p.c_out + idx) = cpk;
        rs[i] += cv0 + cv1 + cv2 + cv3;
      }
    }
    // lanes tn = s, s+4, s+8, s+12 share a row: reduce across bit2/bit3 of tn.
#pragma unroll
    for (int i = 0; i < 4; ++i) {
      float sum = rs[i];
      sum += __shfl_xor(sum, 4);
      sum += __shfl_xor(sum, 8);
      if (t4 == 0)
        atomicAdd(p.S + (size_t)z * 2048 + row0 + i * 16 + s, sum);
    }
  } else {
    // MODE 3: acc = c@v.  Scale rows by 1/(S+1e-8); float4 stores.
#pragma unroll
    for (int i = 0; i < 4; ++i) {
      int n = row0 + i * 16 + s;
      float sc = 1.f / (p.S[(size_t)z * 2048 + n] + 1e-8f);
#pragma unroll
      for (int j = 0; j < 4; ++j) {
        float v[4] = {acc[i][j][0], acc[i][j][1], acc[i][j][2], acc[i][j][3]};
        quad_transpose(v, s);
        int d0 = colbase + j * 16 + t4;
        float4 o;
        o.x = v[0] * sc; o.y = v[1] * sc; o.z = v[2] * sc; o.w = v[3] * sc;
        *(float4*)(p.field + ((size_t)z * 2048 + n) * 1024 + d0) = o;
      }
    }
  }
}

__global__ void cvt_bf16(const float* __restrict__ src, ushort* __restrict__ dst, int n4) {
  int i = blockIdx.x * blockDim.x + threadIdx.x;
  if (i < n4) {
    float4 f = ((const float4*)src)[i];
    ushort4 o;
    o.x = f2bf(f.x); o.y = f2bf(f.y); o.z = f2bf(f.z); o.w = f2bf(f.w);
    ((ushort4*)dst)[i] = o;
  }
}

extern "C" void kernel_launch(void* const* d_in, const int* in_sizes, int n_in,
                              void* d_out, int out_size, void* d_ws, size_t ws_size,
                              hipStream_t stream) {
  const float* states = (const float*)d_in[0];
  const float* gates  = (const float*)d_in[1];
  const float* r_acc  = (const float*)d_in[2];
  const float* W_in   = (const float*)d_in[3];
  const float* W_out  = (const float*)d_in[4];
  const float* condp  = (const float*)d_in[5];

  float* field = (float*)d_out;                       // (B,N,D)
  float* r_out = field + (size_t)B_ * N_ * D_;        // (B,N,N)

  char* w = (char*)d_ws;
  ushort* Xb  = (ushort*)w; w += (size_t)B_ * N_ * D_ * 2;   // 33.5 MB
  ushort* Wib = (ushort*)w; w += (size_t)D_ * D_ * 2;        // 2 MB
  ushort* Wob = (ushort*)w; w += (size_t)D_ * D_ * 2;        // 2 MB
  ushort* U   = (ushort*)w; w += (size_t)B_ * N_ * D_ * 2;   // 33.5 MB
  ushort* VT  = (ushort*)w; w += (size_t)B_ * D_ * N_ * 2;   // 33.5 MB
  ushort* C   = (ushort*)w; w += (size_t)B_ * N_ * N_ * 2;   // 67 MB
  float*  S   = (float*)w;                                   // 64 KB

  hipMemsetAsync(S, 0, (size_t)B_ * N_ * 4, stream);

  cvt_bf16<<<dim3(B_ * N_ * D_ / 4 / 256), 256, 0, stream>>>(states, Xb, B_ * N_ * D_ / 4);
  cvt_bf16<<<dim3(D_ * D_ / 4 / 256), 256, 0, stream>>>(W_in, Wib, D_ * D_ / 4);
  cvt_bf16<<<dim3(D_ * D_ / 4 / 256), 256, 0, stream>>>(W_out, Wob, D_ * D_ / 4);

  // GEMM 1a: a = X@W_in^T  -> u
  GParams p0{};
  p0.A = Xb; p0.B = Wib; p0.sAz = 0; p0.sBz = 0;
  p0.lda = D_; p0.ldb = D_; p0.K = D_;
  p0.u_out = U;
  gemm_nt<0><<<dim3(8, 128, 1), 256, 0, stream>>>(p0);

  // GEMM 1b: values = g*(X@W_out^T) -> vT
  GParams p1{};
  p1.A = Xb; p1.B = Wob; p1.sAz = 0; p1.sBz = 0;
  p1.lda = D_; p1.ldb = D_; p1.K = D_;
  p1.gates = gates; p1.vT_out = VT;
  gemm_nt<1><<<dim3(8, 128, 1), 256, 0, stream>>>(p1);

  // GEMM 2: r_inst = u@u^T -> r_new (out), c (ws), S (ws)
  GParams p2{};
  p2.A = U; p2.B = U; p2.sAz = (long)N_ * D_; p2.sBz = (long)N_ * D_;
  p2.lda = D_; p2.ldb = D_; p2.K = D_;
  p2.gates = gates; p2.r_in = r_acc; p2.r_out = r_out;
  p2.c_out = C; p2.S = S; p2.condp = condp;
  gemm_nt<2><<<dim3(16, 16, 8), 256, 0, stream>>>(p2);

  // GEMM 3: field = (c@v) / S
  GParams p3{};
  p3.A = C; p3.B = VT; p3.sAz = (long)N_ * N_; p3.sBz = (long)D_ * N_;
  p3.lda = N_; p3.ldb = N_; p3.K = N_;
  p3.S = S; p3.field = field;
  gemm_nt<3><<<dim3(8, 16, 8), 256, 0, stream>>>(p3);
}